// Round 8
// baseline (461.610 us; speedup 1.0000x reference)
//
#include <hip/hip_runtime.h>
#include <hip/hip_bf16.h>

typedef __attribute__((ext_vector_type(8))) short short8;
typedef __attribute__((ext_vector_type(4))) short short4v;
typedef __attribute__((ext_vector_type(4))) float f32x4;

#define B_ 16
#define T_ 1024
#define C_ 512
#define NH 8
#define HD 64

__device__ __forceinline__ short f2bf(float f) {
  union { float f; unsigned u; } v;
  v.f = f;
  unsigned r = v.u + 0x7fffu + ((v.u >> 16) & 1u);
  return (short)(r >> 16);
}

__device__ __forceinline__ short2 pack_bf2(float a, float b) {
  __hip_bfloat162 t = __float22bfloat162_rn(make_float2(a, b));
  short2 r;
  __builtin_memcpy(&r, &t, 4);
  return r;
}

__device__ __forceinline__ void gload_lds16(const short* g, short* l) {
  __builtin_amdgcn_global_load_lds(
      (const __attribute__((address_space(1))) void*)g,
      (__attribute__((address_space(3))) void*)l, 16, 0, 0);
}

// ---------------- stage 1a: partial sums ----------------
__global__ __launch_bounds__(256) void stats1_kernel(const float* __restrict__ x,
                                                     float2* __restrict__ partials) {
  int chunk = blockIdx.x;
  int b = blockIdx.y;
  int tid = threadIdx.x;
  const float4* xb = (const float4*)(x + (size_t)b * 524288 + (size_t)chunk * 8192);
  float s = 0.f, s2 = 0.f;
#pragma unroll
  for (int i = 0; i < 8; i++) {
    float4 v = xb[tid + i * 256];
    s  += v.x + v.y + v.z + v.w;
    s2 += v.x * v.x + v.y * v.y + v.z * v.z + v.w * v.w;
  }
  __shared__ float ls[256], ls2[256];
  ls[tid] = s; ls2[tid] = s2;
  __syncthreads();
  for (int o = 128; o > 0; o >>= 1) {
    if (tid < o) { ls[tid] += ls[tid + o]; ls2[tid] += ls2[tid + o]; }
    __syncthreads();
  }
  if (tid == 0) partials[b * 64 + chunk] = make_float2(ls[0], ls2[0]);
}

// ---------------- stage 1b: final reduce ----------------
__global__ __launch_bounds__(64) void stats2_kernel(const float2* __restrict__ partials,
                                                    float* __restrict__ stats) {
  int b = blockIdx.x;
  float2 p = partials[b * 64 + threadIdx.x];
  float s = p.x, s2 = p.y;
#pragma unroll
  for (int off = 1; off < 64; off <<= 1) {
    s  += __shfl_xor(s,  off, 64);
    s2 += __shfl_xor(s2, off, 64);
  }
  if (threadIdx.x == 0) {
    float mean = s * (1.f / 524288.f);
    float var  = s2 * (1.f / 524288.f) - mean * mean;
    stats[b * 2]     = mean;
    stats[b * 2 + 1] = rsqrtf(var + 1e-5f);
  }
}

// ---------------- stage 2: normalize + affine -> bf16 ----------------
__global__ __launch_bounds__(256) void norm_kernel(const float* __restrict__ x,
                                                   const float* __restrict__ gamma,
                                                   const float* __restrict__ beta,
                                                   const float* __restrict__ stats,
                                                   short* __restrict__ xn) {
  size_t i4 = (size_t)blockIdx.x * 256 + threadIdx.x;
  float4 v = ((const float4*)x)[i4];
  size_t i = i4 * 4;
  int b = (int)(i >> 19);
  int c = (int)(i & 511);
  float mean = stats[b * 2], rstd = stats[b * 2 + 1];
  short4v o;
  o[0] = f2bf((v.x - mean) * rstd * gamma[c + 0] + beta[c + 0]);
  o[1] = f2bf((v.y - mean) * rstd * gamma[c + 1] + beta[c + 1]);
  o[2] = f2bf((v.z - mean) * rstd * gamma[c + 2] + beta[c + 2]);
  o[3] = f2bf((v.w - mean) * rstd * gamma[c + 3] + beta[c + 3]);
  ((short4v*)xn)[i4] = o;
}

// ---------------- stage 3: weights fp32 (K,N) -> bf16 transposed ----------------
__global__ __launch_bounds__(256) void transpose_w_all(const float* __restrict__ wq,
                                                       const float* __restrict__ wk,
                                                       const float* __restrict__ wv,
                                                       const float* __restrict__ wo,
                                                       short* __restrict__ wqkvT,
                                                       short* __restrict__ woT) {
  int o = blockIdx.x * 256 + threadIdx.x;
  int sel = o >> 18;
  int oo = o & 262143;
  int k = oo >> 9, n = oo & 511;
  const float* w = (sel == 0) ? wq : (sel == 1) ? wk : (sel == 2) ? wv : wo;
  float val = w[oo];
  if (sel < 3) wqkvT[((size_t)(sel * 512 + n)) * 512 + k] = f2bf(val);
  else         woT[(size_t)n * 512 + k] = f2bf(val);
}

// ---------------- stage 4: fused QKV GEMM (m97 structure) ----------------
// Q segment (seg 0) pre-scaled by 0.125 (exact in bf16) to fold softmax scale.
__global__ __launch_bounds__(256) void gemm_qkv(const short* __restrict__ A,
                                                const short* __restrict__ Bt,
                                                const float* __restrict__ bq,
                                                const float* __restrict__ bk,
                                                const float* __restrict__ bv,
                                                short* __restrict__ C) {
  __shared__ __align__(16) short As[128 * 32];
  __shared__ __align__(16) short Bs[128 * 32];
  int tid = threadIdx.x;
  int w = tid >> 6, lane = tid & 63;
  int quad = lane >> 4, l16 = lane & 15;
  int mw = (w >> 1) * 64, nw = (w & 1) * 64;
  int seg = (blockIdx.x * 128) >> 9;
  const float* bias = (seg == 0) ? bq : (seg == 1) ? bk : bv;
  float smul = (seg == 0) ? 0.125f : 1.0f;
  const short* Atile = A + (size_t)(blockIdx.y * 128) * 512;
  const short* Btile = Bt + (size_t)(blockIdx.x * 128) * 512;
  int srow = (w << 4) + (lane >> 2);
  int scol = (lane & 3) * 8;
  f32x4 acc[4][4] = {};
  for (int k0 = 0; k0 < 512; k0 += 32) {
    __syncthreads();
    gload_lds16(&Atile[(size_t)srow * 512 + k0 + scol],        &As[w * 512]);
    gload_lds16(&Atile[(size_t)(srow + 64) * 512 + k0 + scol], &As[2048 + w * 512]);
    gload_lds16(&Btile[(size_t)srow * 512 + k0 + scol],        &Bs[w * 512]);
    gload_lds16(&Btile[(size_t)(srow + 64) * 512 + k0 + scol], &Bs[2048 + w * 512]);
    __syncthreads();
    short8 af[4], bf[4];
#pragma unroll
    for (int i = 0; i < 4; i++) af[i] = *(const short8*)(&As[(mw + i * 16 + l16) * 32 + quad * 8]);
#pragma unroll
    for (int i = 0; i < 4; i++) bf[i] = *(const short8*)(&Bs[(nw + i * 16 + l16) * 32 + quad * 8]);
#pragma unroll
    for (int mi = 0; mi < 4; mi++)
#pragma unroll
      for (int ni = 0; ni < 4; ni++)
        acc[mi][ni] = __builtin_amdgcn_mfma_f32_16x16x32_bf16(af[mi], bf[ni], acc[mi][ni], 0, 0, 0);
  }
  int m0 = blockIdx.y * 128 + mw;
  int n0 = blockIdx.x * 128 + nw;
#pragma unroll
  for (int mi = 0; mi < 4; mi++)
#pragma unroll
    for (int ni = 0; ni < 4; ni++) {
      int col = n0 + ni * 16 + l16;
      float bval = bias[col & 511];
#pragma unroll
      for (int r = 0; r < 4; r++) {
        int row = m0 + mi * 16 + quad * 4 + r;
        C[(size_t)row * 1536 + col] = f2bf((acc[mi][ni][r] + bval) * smul);
      }
    }
}

// ---------------- stage 6: GEMM + bias + residual (fp32 out) ----------------
__global__ __launch_bounds__(256) void gemm_out(const short* __restrict__ A,
                                                const short* __restrict__ Bt,
                                                const float* __restrict__ bias,
                                                const float* __restrict__ xres,
                                                float* __restrict__ out) {
  __shared__ __align__(16) short As[128 * 32];
  __shared__ __align__(16) short Bs[128 * 32];
  int tid = threadIdx.x;
  int w = tid >> 6, lane = tid & 63;
  int quad = lane >> 4, l16 = lane & 15;
  int mw = (w >> 1) * 64, nw = (w & 1) * 64;
  const short* Atile = A + (size_t)(blockIdx.y * 128) * 512;
  const short* Btile = Bt + (size_t)(blockIdx.x * 128) * 512;
  int srow = (w << 4) + (lane >> 2);
  int scol = (lane & 3) * 8;
  f32x4 acc[4][4] = {};
  for (int k0 = 0; k0 < 512; k0 += 32) {
    __syncthreads();
    gload_lds16(&Atile[(size_t)srow * 512 + k0 + scol],        &As[w * 512]);
    gload_lds16(&Atile[(size_t)(srow + 64) * 512 + k0 + scol], &As[2048 + w * 512]);
    gload_lds16(&Btile[(size_t)srow * 512 + k0 + scol],        &Bs[w * 512]);
    gload_lds16(&Btile[(size_t)(srow + 64) * 512 + k0 + scol], &Bs[2048 + w * 512]);
    __syncthreads();
    short8 af[4], bf[4];
#pragma unroll
    for (int i = 0; i < 4; i++) af[i] = *(const short8*)(&As[(mw + i * 16 + l16) * 32 + quad * 8]);
#pragma unroll
    for (int i = 0; i < 4; i++) bf[i] = *(const short8*)(&Bs[(nw + i * 16 + l16) * 32 + quad * 8]);
#pragma unroll
    for (int mi = 0; mi < 4; mi++)
#pragma unroll
      for (int ni = 0; ni < 4; ni++)
        acc[mi][ni] = __builtin_amdgcn_mfma_f32_16x16x32_bf16(af[mi], bf[ni], acc[mi][ni], 0, 0, 0);
  }
  int m0 = blockIdx.y * 128 + mw;
  int n0 = blockIdx.x * 128 + nw;
#pragma unroll
  for (int mi = 0; mi < 4; mi++)
#pragma unroll
    for (int ni = 0; ni < 4; ni++) {
      int col = n0 + ni * 16 + l16;
      float bval = bias[col];
#pragma unroll
      for (int r = 0; r < 4; r++) {
        int row = m0 + mi * 16 + quad * 4 + r;
        out[(size_t)row * 512 + col] = acc[mi][ni][r] + bval + xres[(size_t)row * 512 + col];
      }
    }
}

// ---------------- stage 4b: V -> vT[b][h][d][slot-permuted keys] ----------------
// Slot layout per 128-key chunk: slot = w*32 + q*8 + half*4 + r for key
// kt = half*64 + w*16 + q*4 + r, so attn's PV A-frag (wave w, quad q) is one b128.
__global__ __launch_bounds__(256) void vtrans_kernel(const short* __restrict__ qkv,
                                                     short* __restrict__ vT) {
  int chunk = blockIdx.x;  // 0..7 (128-token chunks)
  int h  = blockIdx.y;
  int b  = blockIdx.z;
  int tid = threadIdx.x;
  __shared__ short TB[128 * 72];
  const short* src = qkv + ((size_t)b * T_ + chunk * 128) * 1536 + 1024 + (size_t)h * 64;
#pragma unroll
  for (int i = 0; i < 4; i++) {
    int idx = tid + i * 256;
    int t = idx >> 3, c = idx & 7;
    *(short8*)(&TB[t * 72 + c * 8]) = *(const short8*)(src + (size_t)t * 1536 + c * 8);
  }
  __syncthreads();
  short* dst = vT + ((size_t)(b * 8 + h) * 64) * 1024 + chunk * 128;
#pragma unroll
  for (int i = 0; i < 4; i++) {
    int idx = tid + i * 256;
    int d = idx >> 4, sc = idx & 15;
    int w2 = sc >> 2, q2 = sc & 3;
    short8 o;
#pragma unroll
    for (int sg = 0; sg < 8; sg++) {
      int half = sg >> 2, r = sg & 3;
      o[sg] = TB[(half * 64 + w2 * 16 + q2 * 4 + r) * 72 + d];
    }
    *(short8*)(dst + (size_t)d * 1024 + sc * 8) = o;
  }
}

// ---------------- stage 5: attention — DMA-staged, swizzled, P-free ----------------
// K/V staged via global_load_lds with the bank swizzle applied on the GLOBAL
// address side (LDS dst must be contiguous). Waves split keys (32/wave/iter);
// Q in registers; S^T output feeds PV directly (no P LDS round-trip).
__global__ __launch_bounds__(256, 4) void attn_kernel(const short* __restrict__ Q,
                                                      const short* __restrict__ Kmat,
                                                      const short* __restrict__ vTg,
                                                      short* __restrict__ O) {
  int tid = threadIdx.x;
  int w = tid >> 6, lane = tid & 63;
  int quad = lane >> 4, l16 = lane & 15;
  int bh = blockIdx.x;   // b*8+h
  int qt = blockIdx.y;
  int b = bh >> 3, h = bh & 7;
  size_t base  = ((size_t)b * T_) * 1536 + (size_t)h * 64;
  size_t vbase = ((size_t)bh * 64) * 1024;
  size_t obase = ((size_t)b * T_) * 512 + (size_t)h * 64;
  int qrow0 = qt * 64;

  __shared__ __align__(16) char smem[32768 + 1024];
  short* KT = (short*)smem;                 // 128 keys x 8 dcol-slots x 8 (swizzled)
  short* VT = (short*)(smem + 16384);       // 64 d x 16 kcol-slots x 8 (swizzled)
  float* Lbuf = (float*)smem;               // epilogue union [q][d] pad 68
  float* denomL = (float*)(smem + 32768);

  // Q as B-frags: B[k=d=quad*8+j][n=q=l16], 4 q-tiles x 2 d-halves
  short8 qf0[4], qf1[4];
#pragma unroll
  for (int g = 0; g < 4; g++) {
    const short* qp = Q + base + (size_t)(qrow0 + g * 16 + l16) * 1536 + quad * 8;
    qf0[g] = *(const short8*)qp;
    qf1[g] = *(const short8*)(qp + 32);
  }

  // staging descriptors: lane's 16B block index bk = w*256 + n*64 + lane
  const short* ksrc[4];
  const short* vsrc[4];
#pragma unroll
  for (int n = 0; n < 4; n++) {
    int bk = w * 256 + n * 64 + lane;
    int key = bk >> 3, jc = bk & 7;
    int dcol = jc ^ (key & 7);
    ksrc[n] = Kmat + base + (size_t)key * 1536 + dcol * 8;
    int d = bk >> 4, j = bk & 15;
    int kc = j ^ (d & 15);
    vsrc[n] = vTg + vbase + (size_t)d * 1024 + kc * 8;
  }

  // fragment LDS offsets (shorts), loop-invariant
  int l7 = l16 & 7;
  int kA0 = ((w * 16 + l16) * 8 + (quad ^ l7)) * 8;
  int kA1 = ((w * 16 + l16) * 8 + ((quad + 4) ^ l7)) * 8;
  int kB0 = kA0 + 4096;   // key + 64
  int kB1 = kA1 + 4096;
  int vOff = (l16 * 16 + ((w * 4 + quad) ^ l16)) * 8;

  f32x4 oacc[4][4] = {};   // O^T[d-tile f][q-tile g]
  float lsum[4] = {0.f, 0.f, 0.f, 0.f};

  for (int kk0 = 0; kk0 < T_; kk0 += 128) {
    __syncthreads();   // previous tile fully consumed
#pragma unroll
    for (int n = 0; n < 4; n++)
      gload_lds16(ksrc[n] + (size_t)kk0 * 1536, KT + (w * 256 + n * 64) * 8);
#pragma unroll
    for (int n = 0; n < 4; n++)
      gload_lds16(vsrc[n] + kk0, VT + (w * 256 + n * 64) * 8);
    __syncthreads();   // compiler drains vmcnt before barrier

    short8 kfa0 = *(const short8*)(KT + kA0);
    short8 kfa1 = *(const short8*)(KT + kA1);
    short8 kfb0 = *(const short8*)(KT + kB0);
    short8 kfb1 = *(const short8*)(KT + kB1);
    short8 vfr[4];
#pragma unroll
    for (int f = 0; f < 4; f++) vfr[f] = *(const short8*)(VT + vOff + f * 2048);

#pragma unroll
    for (int g = 0; g < 4; g++) {
      f32x4 za = {}, zb = {};
      za = __builtin_amdgcn_mfma_f32_16x16x32_bf16(kfa0, qf0[g], za, 0, 0, 0);
      za = __builtin_amdgcn_mfma_f32_16x16x32_bf16(kfa1, qf1[g], za, 0, 0, 0);
      zb = __builtin_amdgcn_mfma_f32_16x16x32_bf16(kfb0, qf0[g], zb, 0, 0, 0);
      zb = __builtin_amdgcn_mfma_f32_16x16x32_bf16(kfb1, qf1[g], zb, 0, 0, 0);
      float pa0 = __expf(za[0]), pa1 = __expf(za[1]);
      float pa2 = __expf(za[2]), pa3 = __expf(za[3]);
      float pb0 = __expf(zb[0]), pb1 = __expf(zb[1]);
      float pb2 = __expf(zb[2]), pb3 = __expf(zb[3]);
      lsum[g] += (pa0 + pa1) + (pa2 + pa3) + (pb0 + pb1) + (pb2 + pb3);
      short2 a01 = pack_bf2(pa0, pa1), a23 = pack_bf2(pa2, pa3);
      short2 b01 = pack_bf2(pb0, pb1), b23 = pack_bf2(pb2, pb3);
      short8 pf;
      pf[0] = a01.x; pf[1] = a01.y; pf[2] = a23.x; pf[3] = a23.y;
      pf[4] = b01.x; pf[5] = b01.y; pf[6] = b23.x; pf[7] = b23.y;
#pragma unroll
      for (int f = 0; f < 4; f++)
        oacc[f][g] = __builtin_amdgcn_mfma_f32_16x16x32_bf16(vfr[f], pf, oacc[f][g], 0, 0, 0);
    }
  }

  // per-lane lsum covers this wave's keys for query g*16+l16; sum over quads
#pragma unroll
  for (int g = 0; g < 4; g++) {
    lsum[g] += __shfl_xor(lsum[g], 16, 64);
    lsum[g] += __shfl_xor(lsum[g], 32, 64);
  }
  if (quad == 0) {
#pragma unroll
    for (int g = 0; g < 4; g++) denomL[w * 64 + g * 16 + l16] = lsum[g];
  }
  // sequential cross-wave accumulation of O^T into Lbuf (transposed to [q][d])
  for (int ww = 0; ww < 4; ww++) {
    __syncthreads();
    if (w == ww) {
#pragma unroll
      for (int g = 0; g < 4; g++)
#pragma unroll
        for (int f = 0; f < 4; f++) {
          float* p = &Lbuf[(g * 16 + l16) * 68 + f * 16 + quad * 4];
          if (ww == 0) *(f32x4*)p = oacc[f][g];
          else         *(f32x4*)p = *(f32x4*)p + oacc[f][g];
        }
    }
  }
  __syncthreads();

  // coalesced writeout: thread -> (q = tid/4, 16-wide d segment)
  int q = tid >> 2, seg = tid & 3;
  float dn = denomL[q] + denomL[64 + q] + denomL[128 + q] + denomL[192 + q];
  float rinv = __frcp_rn(dn);
  const float* row = &Lbuf[q * 68 + seg * 16];
  short8 o0, o1;
#pragma unroll
  for (int i = 0; i < 8; i++) o0[i] = f2bf(row[i] * rinv);
#pragma unroll
  for (int i = 0; i < 8; i++) o1[i] = f2bf(row[8 + i] * rinv);
  short* op = O + obase + (size_t)(qrow0 + q) * 512 + seg * 16;
  *(short8*)op = o0;
  *(short8*)(op + 8) = o1;
}

extern "C" void kernel_launch(void* const* d_in, const int* in_sizes, int n_in,
                              void* d_out, int out_size, void* d_ws, size_t ws_size,
                              hipStream_t stream) {
  const float* x     = (const float*)d_in[0];
  const float* gamma = (const float*)d_in[1];
  const float* beta  = (const float*)d_in[2];
  const float* wq    = (const float*)d_in[3];
  const float* bq    = (const float*)d_in[4];
  const float* wk    = (const float*)d_in[5];
  const float* bk    = (const float*)d_in[6];
  const float* wv    = (const float*)d_in[7];
  const float* bv    = (const float*)d_in[8];
  const float* wo    = (const float*)d_in[9];
  const float* bo    = (const float*)d_in[10];
  float* out = (float*)d_out;

  char* ws = (char*)d_ws;
  const size_t XN_ELEMS = (size_t)B_ * T_ * C_;
  size_t off = 0;
  float* stats = (float*)(ws + off); off += 256;
  float2* partials = (float2*)(ws + off); off += 16 * 64 * sizeof(float2);
  short* xn    = (short*)(ws + off); off += XN_ELEMS * 2;
  short* wqkvT = (short*)(ws + off); off += (size_t)1536 * 512 * 2;
  short* woT   = (short*)(ws + off); off += (size_t)512 * 512 * 2;
  short* qkv   = (short*)(ws + off); off += (size_t)B_ * T_ * 1536 * 2;
  short* vTb   = (short*)(ws + off); off += XN_ELEMS * 2;
  short* ao    = (short*)(ws + off); off += XN_ELEMS * 2;

  stats1_kernel<<<dim3(64, 16), 256, 0, stream>>>(x, partials);
  stats2_kernel<<<16, 64, 0, stream>>>(partials, stats);
  norm_kernel<<<8192, 256, 0, stream>>>(x, gamma, beta, stats, xn);
  transpose_w_all<<<4096, 256, 0, stream>>>(wq, wk, wv, wo, wqkvT, woT);

  gemm_qkv<<<dim3(12, 128), 256, 0, stream>>>(xn, wqkvT, bq, bk, bv, qkv);

  vtrans_kernel<<<dim3(8, 8, 16), 256, 0, stream>>>(qkv, vTb);
  attn_kernel<<<dim3(128, 16), 256, 0, stream>>>(qkv, qkv + 512, vTb, ao);

  gemm_out<<<dim3(4, 128), 256, 0, stream>>>(ao, woT, bo, x, out);
}

// Round 9
// 250.731 us; speedup vs baseline: 1.8411x; 1.8411x over previous
//
#include <hip/hip_runtime.h>
#include <hip/hip_bf16.h>

typedef __attribute__((ext_vector_type(8))) short short8;
typedef __attribute__((ext_vector_type(4))) short short4v;
typedef __attribute__((ext_vector_type(4))) float f32x4;

#define B_ 16
#define T_ 1024
#define C_ 512
#define NH 8
#define HD 64

__device__ __forceinline__ short f2bf(float f) {
  union { float f; unsigned u; } v;
  v.f = f;
  unsigned r = v.u + 0x7fffu + ((v.u >> 16) & 1u);
  return (short)(r >> 16);
}

__device__ __forceinline__ short2 pack_bf2(float a, float b) {
  __hip_bfloat162 t = __float22bfloat162_rn(make_float2(a, b));
  short2 r;
  __builtin_memcpy(&r, &t, 4);
  return r;
}

__device__ __forceinline__ void gload_lds16(const short* g, short* l) {
  __builtin_amdgcn_global_load_lds(
      (const __attribute__((address_space(1))) void*)g,
      (__attribute__((address_space(3))) void*)l, 16, 0, 0);
}

// ---------------- stage 1a: partial sums ----------------
__global__ __launch_bounds__(256) void stats1_kernel(const float* __restrict__ x,
                                                     float2* __restrict__ partials) {
  int chunk = blockIdx.x;
  int b = blockIdx.y;
  int tid = threadIdx.x;
  const float4* xb = (const float4*)(x + (size_t)b * 524288 + (size_t)chunk * 8192);
  float s = 0.f, s2 = 0.f;
#pragma unroll
  for (int i = 0; i < 8; i++) {
    float4 v = xb[tid + i * 256];
    s  += v.x + v.y + v.z + v.w;
    s2 += v.x * v.x + v.y * v.y + v.z * v.z + v.w * v.w;
  }
  __shared__ float ls[256], ls2[256];
  ls[tid] = s; ls2[tid] = s2;
  __syncthreads();
  for (int o = 128; o > 0; o >>= 1) {
    if (tid < o) { ls[tid] += ls[tid + o]; ls2[tid] += ls2[tid + o]; }
    __syncthreads();
  }
  if (tid == 0) partials[b * 64 + chunk] = make_float2(ls[0], ls2[0]);
}

// ---------------- stage 1b: final reduce ----------------
__global__ __launch_bounds__(64) void stats2_kernel(const float2* __restrict__ partials,
                                                    float* __restrict__ stats) {
  int b = blockIdx.x;
  float2 p = partials[b * 64 + threadIdx.x];
  float s = p.x, s2 = p.y;
#pragma unroll
  for (int off = 1; off < 64; off <<= 1) {
    s  += __shfl_xor(s,  off, 64);
    s2 += __shfl_xor(s2, off, 64);
  }
  if (threadIdx.x == 0) {
    float mean = s * (1.f / 524288.f);
    float var  = s2 * (1.f / 524288.f) - mean * mean;
    stats[b * 2]     = mean;
    stats[b * 2 + 1] = rsqrtf(var + 1e-5f);
  }
}

// ---------------- stage 2: normalize + affine -> bf16 ----------------
__global__ __launch_bounds__(256) void norm_kernel(const float* __restrict__ x,
                                                   const float* __restrict__ gamma,
                                                   const float* __restrict__ beta,
                                                   const float* __restrict__ stats,
                                                   short* __restrict__ xn) {
  size_t i4 = (size_t)blockIdx.x * 256 + threadIdx.x;
  float4 v = ((const float4*)x)[i4];
  size_t i = i4 * 4;
  int b = (int)(i >> 19);
  int c = (int)(i & 511);
  float mean = stats[b * 2], rstd = stats[b * 2 + 1];
  short4v o;
  o[0] = f2bf((v.x - mean) * rstd * gamma[c + 0] + beta[c + 0]);
  o[1] = f2bf((v.y - mean) * rstd * gamma[c + 1] + beta[c + 1]);
  o[2] = f2bf((v.z - mean) * rstd * gamma[c + 2] + beta[c + 2]);
  o[3] = f2bf((v.w - mean) * rstd * gamma[c + 3] + beta[c + 3]);
  ((short4v*)xn)[i4] = o;
}

// ---------------- stage 3: weights fp32 (K,N) -> bf16 transposed ----------------
__global__ __launch_bounds__(256) void transpose_w_all(const float* __restrict__ wq,
                                                       const float* __restrict__ wk,
                                                       const float* __restrict__ wv,
                                                       const float* __restrict__ wo,
                                                       short* __restrict__ wqkvT,
                                                       short* __restrict__ woT) {
  int o = blockIdx.x * 256 + threadIdx.x;
  int sel = o >> 18;
  int oo = o & 262143;
  int k = oo >> 9, n = oo & 511;
  const float* w = (sel == 0) ? wq : (sel == 1) ? wk : (sel == 2) ? wv : wo;
  float val = w[oo];
  if (sel < 3) wqkvT[((size_t)(sel * 512 + n)) * 512 + k] = f2bf(val);
  else         woT[(size_t)n * 512 + k] = f2bf(val);
}

// ---------------- stage 4: fused QKV GEMM (m97 structure) ----------------
// Q segment (seg 0) pre-scaled by 0.125 (exact in bf16) to fold softmax scale.
__global__ __launch_bounds__(256) void gemm_qkv(const short* __restrict__ A,
                                                const short* __restrict__ Bt,
                                                const float* __restrict__ bq,
                                                const float* __restrict__ bk,
                                                const float* __restrict__ bv,
                                                short* __restrict__ C) {
  __shared__ __align__(16) short As[128 * 32];
  __shared__ __align__(16) short Bs[128 * 32];
  int tid = threadIdx.x;
  int w = tid >> 6, lane = tid & 63;
  int quad = lane >> 4, l16 = lane & 15;
  int mw = (w >> 1) * 64, nw = (w & 1) * 64;
  int seg = (blockIdx.x * 128) >> 9;
  const float* bias = (seg == 0) ? bq : (seg == 1) ? bk : bv;
  float smul = (seg == 0) ? 0.125f : 1.0f;
  const short* Atile = A + (size_t)(blockIdx.y * 128) * 512;
  const short* Btile = Bt + (size_t)(blockIdx.x * 128) * 512;
  int srow = (w << 4) + (lane >> 2);
  int scol = (lane & 3) * 8;
  f32x4 acc[4][4] = {};
  for (int k0 = 0; k0 < 512; k0 += 32) {
    __syncthreads();
    gload_lds16(&Atile[(size_t)srow * 512 + k0 + scol],        &As[w * 512]);
    gload_lds16(&Atile[(size_t)(srow + 64) * 512 + k0 + scol], &As[2048 + w * 512]);
    gload_lds16(&Btile[(size_t)srow * 512 + k0 + scol],        &Bs[w * 512]);
    gload_lds16(&Btile[(size_t)(srow + 64) * 512 + k0 + scol], &Bs[2048 + w * 512]);
    __syncthreads();
    short8 af[4], bf[4];
#pragma unroll
    for (int i = 0; i < 4; i++) af[i] = *(const short8*)(&As[(mw + i * 16 + l16) * 32 + quad * 8]);
#pragma unroll
    for (int i = 0; i < 4; i++) bf[i] = *(const short8*)(&Bs[(nw + i * 16 + l16) * 32 + quad * 8]);
#pragma unroll
    for (int mi = 0; mi < 4; mi++)
#pragma unroll
      for (int ni = 0; ni < 4; ni++)
        acc[mi][ni] = __builtin_amdgcn_mfma_f32_16x16x32_bf16(af[mi], bf[ni], acc[mi][ni], 0, 0, 0);
  }
  int m0 = blockIdx.y * 128 + mw;
  int n0 = blockIdx.x * 128 + nw;
#pragma unroll
  for (int mi = 0; mi < 4; mi++)
#pragma unroll
    for (int ni = 0; ni < 4; ni++) {
      int col = n0 + ni * 16 + l16;
      float bval = bias[col & 511];
#pragma unroll
      for (int r = 0; r < 4; r++) {
        int row = m0 + mi * 16 + quad * 4 + r;
        C[(size_t)row * 1536 + col] = f2bf((acc[mi][ni][r] + bval) * smul);
      }
    }
}

// ---------------- stage 6: GEMM + bias + residual (fp32 out) ----------------
__global__ __launch_bounds__(256) void gemm_out(const short* __restrict__ A,
                                                const short* __restrict__ Bt,
                                                const float* __restrict__ bias,
                                                const float* __restrict__ xres,
                                                float* __restrict__ out) {
  __shared__ __align__(16) short As[128 * 32];
  __shared__ __align__(16) short Bs[128 * 32];
  int tid = threadIdx.x;
  int w = tid >> 6, lane = tid & 63;
  int quad = lane >> 4, l16 = lane & 15;
  int mw = (w >> 1) * 64, nw = (w & 1) * 64;
  const short* Atile = A + (size_t)(blockIdx.y * 128) * 512;
  const short* Btile = Bt + (size_t)(blockIdx.x * 128) * 512;
  int srow = (w << 4) + (lane >> 2);
  int scol = (lane & 3) * 8;
  f32x4 acc[4][4] = {};
  for (int k0 = 0; k0 < 512; k0 += 32) {
    __syncthreads();
    gload_lds16(&Atile[(size_t)srow * 512 + k0 + scol],        &As[w * 512]);
    gload_lds16(&Atile[(size_t)(srow + 64) * 512 + k0 + scol], &As[2048 + w * 512]);
    gload_lds16(&Btile[(size_t)srow * 512 + k0 + scol],        &Bs[w * 512]);
    gload_lds16(&Btile[(size_t)(srow + 64) * 512 + k0 + scol], &Bs[2048 + w * 512]);
    __syncthreads();
    short8 af[4], bf[4];
#pragma unroll
    for (int i = 0; i < 4; i++) af[i] = *(const short8*)(&As[(mw + i * 16 + l16) * 32 + quad * 8]);
#pragma unroll
    for (int i = 0; i < 4; i++) bf[i] = *(const short8*)(&Bs[(nw + i * 16 + l16) * 32 + quad * 8]);
#pragma unroll
    for (int mi = 0; mi < 4; mi++)
#pragma unroll
      for (int ni = 0; ni < 4; ni++)
        acc[mi][ni] = __builtin_amdgcn_mfma_f32_16x16x32_bf16(af[mi], bf[ni], acc[mi][ni], 0, 0, 0);
  }
  int m0 = blockIdx.y * 128 + mw;
  int n0 = blockIdx.x * 128 + nw;
#pragma unroll
  for (int mi = 0; mi < 4; mi++)
#pragma unroll
    for (int ni = 0; ni < 4; ni++) {
      int col = n0 + ni * 16 + l16;
      float bval = bias[col];
#pragma unroll
      for (int r = 0; r < 4; r++) {
        int row = m0 + mi * 16 + quad * 4 + r;
        out[(size_t)row * 512 + col] = acc[mi][ni][r] + bval + xres[(size_t)row * 512 + col];
      }
    }
}

// ---------------- stage 4b: V -> vT[b][h][d][slot-permuted keys] ----------------
// Slot layout per 128-key chunk: slot = w*32 + q*8 + half*4 + r for key
// kt = half*64 + w*16 + q*4 + r, so attn's PV A-frag (wave w, quad q) is one b128.
__global__ __launch_bounds__(256) void vtrans_kernel(const short* __restrict__ qkv,
                                                     short* __restrict__ vT) {
  int chunk = blockIdx.x;  // 0..7 (128-token chunks)
  int h  = blockIdx.y;
  int b  = blockIdx.z;
  int tid = threadIdx.x;
  __shared__ short TB[128 * 72];
  const short* src = qkv + ((size_t)b * T_ + chunk * 128) * 1536 + 1024 + (size_t)h * 64;
#pragma unroll
  for (int i = 0; i < 4; i++) {
    int idx = tid + i * 256;
    int t = idx >> 3, c = idx & 7;
    *(short8*)(&TB[t * 72 + c * 8]) = *(const short8*)(src + (size_t)t * 1536 + c * 8);
  }
  __syncthreads();
  short* dst = vT + ((size_t)(b * 8 + h) * 64) * 1024 + chunk * 128;
#pragma unroll
  for (int i = 0; i < 4; i++) {
    int idx = tid + i * 256;
    int d = idx >> 4, sc = idx & 15;
    int w2 = sc >> 2, q2 = sc & 3;
    short8 o;
#pragma unroll
    for (int sg = 0; sg < 8; sg++) {
      int half = sg >> 2, r = sg & 3;
      o[sg] = TB[(half * 64 + w2 * 16 + q2 * 4 + r) * 72 + d];
    }
    *(short8*)(dst + (size_t)d * 1024 + sc * 8) = o;
  }
}

// ---------------- stage 5: attention — DMA-staged, swizzled, P-free ----------------
// K/V staged via global_load_lds with the bank swizzle applied on the GLOBAL
// address side (LDS dst must be contiguous). Waves split keys (32/wave/iter);
// Q in registers; S^T output feeds PV directly (no P LDS round-trip).
// NOTE: no min-waves clamp — this kernel needs ~160 VGPRs; clamping to 128
// (launch_bounds 256,4) forced ~100-reg spills -> 681 MB scratch writes (r8).
__global__ __launch_bounds__(256) void attn_kernel(const short* __restrict__ Q,
                                                   const short* __restrict__ Kmat,
                                                   const short* __restrict__ vTg,
                                                   short* __restrict__ O) {
  int tid = threadIdx.x;
  int w = tid >> 6, lane = tid & 63;
  int quad = lane >> 4, l16 = lane & 15;
  int bh = blockIdx.x;   // b*8+h
  int qt = blockIdx.y;
  int b = bh >> 3, h = bh & 7;
  size_t base  = ((size_t)b * T_) * 1536 + (size_t)h * 64;
  size_t vbase = ((size_t)bh * 64) * 1024;
  size_t obase = ((size_t)b * T_) * 512 + (size_t)h * 64;
  int qrow0 = qt * 64;

  __shared__ __align__(16) char smem[32768 + 1024];
  short* KT = (short*)smem;                 // 128 keys x 8 dcol-slots x 8 (swizzled)
  short* VT = (short*)(smem + 16384);       // 64 d x 16 kcol-slots x 8 (swizzled)
  float* Lbuf = (float*)smem;               // epilogue union [q][d] pad 68
  float* denomL = (float*)(smem + 32768);

  // Q as B-frags: B[k=d=quad*8+j][n=q=l16], 4 q-tiles x 2 d-halves
  short8 qf0[4], qf1[4];
#pragma unroll
  for (int g = 0; g < 4; g++) {
    const short* qp = Q + base + (size_t)(qrow0 + g * 16 + l16) * 1536 + quad * 8;
    qf0[g] = *(const short8*)qp;
    qf1[g] = *(const short8*)(qp + 32);
  }

  // staging descriptors: lane's 16B block index bk = w*256 + n*64 + lane
  const short* ksrc[4];
  const short* vsrc[4];
#pragma unroll
  for (int n = 0; n < 4; n++) {
    int bk = w * 256 + n * 64 + lane;
    int key = bk >> 3, jc = bk & 7;
    int dcol = jc ^ (key & 7);
    ksrc[n] = Kmat + base + (size_t)key * 1536 + dcol * 8;
    int d = bk >> 4, j = bk & 15;
    int kc = j ^ (d & 15);
    vsrc[n] = vTg + vbase + (size_t)d * 1024 + kc * 8;
  }

  // fragment LDS offsets (shorts), loop-invariant
  int l7 = l16 & 7;
  int kA0 = ((w * 16 + l16) * 8 + (quad ^ l7)) * 8;
  int kA1 = ((w * 16 + l16) * 8 + ((quad + 4) ^ l7)) * 8;
  int kB0 = kA0 + 4096;   // key + 64
  int kB1 = kA1 + 4096;
  int vOff = (l16 * 16 + ((w * 4 + quad) ^ l16)) * 8;

  f32x4 oacc[4][4] = {};   // O^T[d-tile f][q-tile g]
  float lsum[4] = {0.f, 0.f, 0.f, 0.f};

  for (int kk0 = 0; kk0 < T_; kk0 += 128) {
    __syncthreads();   // previous tile fully consumed
#pragma unroll
    for (int n = 0; n < 4; n++)
      gload_lds16(ksrc[n] + (size_t)kk0 * 1536, KT + (w * 256 + n * 64) * 8);
#pragma unroll
    for (int n = 0; n < 4; n++)
      gload_lds16(vsrc[n] + kk0, VT + (w * 256 + n * 64) * 8);
    __syncthreads();   // compiler drains vmcnt before barrier

    short8 kfa0 = *(const short8*)(KT + kA0);
    short8 kfa1 = *(const short8*)(KT + kA1);
    short8 kfb0 = *(const short8*)(KT + kB0);
    short8 kfb1 = *(const short8*)(KT + kB1);
    short8 vfr[4];
#pragma unroll
    for (int f = 0; f < 4; f++) vfr[f] = *(const short8*)(VT + vOff + f * 2048);

#pragma unroll
    for (int g = 0; g < 4; g++) {
      f32x4 za = {}, zb = {};
      za = __builtin_amdgcn_mfma_f32_16x16x32_bf16(kfa0, qf0[g], za, 0, 0, 0);
      za = __builtin_amdgcn_mfma_f32_16x16x32_bf16(kfa1, qf1[g], za, 0, 0, 0);
      zb = __builtin_amdgcn_mfma_f32_16x16x32_bf16(kfb0, qf0[g], zb, 0, 0, 0);
      zb = __builtin_amdgcn_mfma_f32_16x16x32_bf16(kfb1, qf1[g], zb, 0, 0, 0);
      float pa0 = __expf(za[0]), pa1 = __expf(za[1]);
      float pa2 = __expf(za[2]), pa3 = __expf(za[3]);
      float pb0 = __expf(zb[0]), pb1 = __expf(zb[1]);
      float pb2 = __expf(zb[2]), pb3 = __expf(zb[3]);
      lsum[g] += (pa0 + pa1) + (pa2 + pa3) + (pb0 + pb1) + (pb2 + pb3);
      short2 a01 = pack_bf2(pa0, pa1), a23 = pack_bf2(pa2, pa3);
      short2 b01 = pack_bf2(pb0, pb1), b23 = pack_bf2(pb2, pb3);
      short8 pf;
      pf[0] = a01.x; pf[1] = a01.y; pf[2] = a23.x; pf[3] = a23.y;
      pf[4] = b01.x; pf[5] = b01.y; pf[6] = b23.x; pf[7] = b23.y;
#pragma unroll
      for (int f = 0; f < 4; f++)
        oacc[f][g] = __builtin_amdgcn_mfma_f32_16x16x32_bf16(vfr[f], pf, oacc[f][g], 0, 0, 0);
    }
  }

  // per-lane lsum covers this wave's keys for query g*16+l16; sum over quads
#pragma unroll
  for (int g = 0; g < 4; g++) {
    lsum[g] += __shfl_xor(lsum[g], 16, 64);
    lsum[g] += __shfl_xor(lsum[g], 32, 64);
  }
  if (quad == 0) {
#pragma unroll
    for (int g = 0; g < 4; g++) denomL[w * 64 + g * 16 + l16] = lsum[g];
  }
  // sequential cross-wave accumulation of O^T into Lbuf (transposed to [q][d])
  for (int ww = 0; ww < 4; ww++) {
    __syncthreads();
    if (w == ww) {
#pragma unroll
      for (int g = 0; g < 4; g++)
#pragma unroll
        for (int f = 0; f < 4; f++) {
          float* p = &Lbuf[(g * 16 + l16) * 68 + f * 16 + quad * 4];
          if (ww == 0) *(f32x4*)p = oacc[f][g];
          else         *(f32x4*)p = *(f32x4*)p + oacc[f][g];
        }
    }
  }
  __syncthreads();

  // coalesced writeout: thread -> (q = tid/4, 16-wide d segment)
  int q = tid >> 2, seg = tid & 3;
  float dn = denomL[q] + denomL[64 + q] + denomL[128 + q] + denomL[192 + q];
  float rinv = __frcp_rn(dn);
  const float* row = &Lbuf[q * 68 + seg * 16];
  short8 o0, o1;
#pragma unroll
  for (int i = 0; i < 8; i++) o0[i] = f2bf(row[i] * rinv);
#pragma unroll
  for (int i = 0; i < 8; i++) o1[i] = f2bf(row[8 + i] * rinv);
  short* op = O + obase + (size_t)(qrow0 + q) * 512 + seg * 16;
  *(short8*)op = o0;
  *(short8*)(op + 8) = o1;
}

extern "C" void kernel_launch(void* const* d_in, const int* in_sizes, int n_in,
                              void* d_out, int out_size, void* d_ws, size_t ws_size,
                              hipStream_t stream) {
  const float* x     = (const float*)d_in[0];
  const float* gamma = (const float*)d_in[1];
  const float* beta  = (const float*)d_in[2];
  const float* wq    = (const float*)d_in[3];
  const float* bq    = (const float*)d_in[4];
  const float* wk    = (const float*)d_in[5];
  const float* bk    = (const float*)d_in[6];
  const float* wv    = (const float*)d_in[7];
  const float* bv    = (const float*)d_in[8];
  const float* wo    = (const float*)d_in[9];
  const float* bo    = (const float*)d_in[10];
  float* out = (float*)d_out;

  char* ws = (char*)d_ws;
  const size_t XN_ELEMS = (size_t)B_ * T_ * C_;
  size_t off = 0;
  float* stats = (float*)(ws + off); off += 256;
  float2* partials = (float2*)(ws + off); off += 16 * 64 * sizeof(float2);
  short* xn    = (short*)(ws + off); off += XN_ELEMS * 2;
  short* wqkvT = (short*)(ws + off); off += (size_t)1536 * 512 * 2;
  short* woT   = (short*)(ws + off); off += (size_t)512 * 512 * 2;
  short* qkv   = (short*)(ws + off); off += (size_t)B_ * T_ * 1536 * 2;
  short* vTb   = (short*)(ws + off); off += XN_ELEMS * 2;
  short* ao    = (short*)(ws + off); off += XN_ELEMS * 2;

  stats1_kernel<<<dim3(64, 16), 256, 0, stream>>>(x, partials);
  stats2_kernel<<<16, 64, 0, stream>>>(partials, stats);
  norm_kernel<<<8192, 256, 0, stream>>>(x, gamma, beta, stats, xn);
  transpose_w_all<<<4096, 256, 0, stream>>>(wq, wk, wv, wo, wqkvT, woT);

  gemm_qkv<<<dim3(12, 128), 256, 0, stream>>>(xn, wqkvT, bq, bk, bv, qkv);

  vtrans_kernel<<<dim3(8, 8, 16), 256, 0, stream>>>(qkv, vTb);
  attn_kernel<<<dim3(128, 16), 256, 0, stream>>>(qkv, qkv + 512, vTb, ao);

  gemm_out<<<dim3(4, 128), 256, 0, stream>>>(ao, woT, bo, x, out);
}